// Round 1
// baseline (137.184 us; speedup 1.0000x reference)
//
#include <hip/hip_runtime.h>

#define LOG2E 1.44269504088896340736f
#define LN2   0.69314718055994530942f

constexpr int BSZ = 2, SEQ = 2048, DM = 1024, DS = 16, DR = 64;
constexpr int NC = 64, CL = SEQ / NC;   // 64 chunks of 32

// Workspace layout (in floats)
constexpr size_t OFF_DT   = 0;                       // [4096][1024]
constexpr size_t OFF_BM   = OFF_DT + (size_t)BSZ*SEQ*DM;      // [4096][16]
constexpr size_t OFF_CM   = OFF_BM + (size_t)BSZ*SEQ*DS;      // [4096][16]
constexpr size_t OFF_S    = OFF_CM + (size_t)BSZ*SEQ*DS;      // [B][NC][1024]
constexpr size_t OFF_HEND = OFF_S  + (size_t)BSZ*NC*DM;       // [B][NC][16][1024]
constexpr size_t OFF_HIN  = OFF_HEND + (size_t)BSZ*NC*DS*DM;  // [B][NC][16][1024]
constexpr size_t OFF_PART = OFF_HEND;  // K2 partials alias hend (used before phase1)
// total = 8,650,752 floats = 34.6 MB

__device__ inline float softplusf(float z) {
  float e = __builtin_amdgcn_exp2f(z * LOG2E);
  if (z > 15.f) return z;
  if (z < -8.f) return e;                      // log1p(e) ~ e
  return __builtin_amdgcn_logf(1.f + e) * LN2; // v_log is log2
}

__device__ inline void fma4(float& acc, float4 a, float4 b) {
  acc = fmaf(a.x, b.x, fmaf(a.y, b.y, fmaf(a.z, b.z, fmaf(a.w, b.w, acc))));
}

// ---------------- K1: dt = softplus(dt_proj_input @ dt_W^T + 2*dt_b) ----------------
// C[4096 x 1024] = A[4096 x 64] * W[1024 x 64]^T ; 64x64 tile per block
__global__ __launch_bounds__(256) void k_dtproj(const float* __restrict__ inp,
                                                const float* __restrict__ W,
                                                const float* __restrict__ bias,
                                                float* __restrict__ dt) {
  __shared__ __align__(16) float At[64][68];  // [k][m]
  __shared__ __align__(16) float Wt[64][68];  // [k][n]
  int mt = blockIdx.x >> 4, nt = blockIdx.x & 15;
  int m0 = mt * 64, d0 = nt * 64;
  int t = threadIdx.x;
  const float4* Ag = (const float4*)(inp + (size_t)m0 * DR);
  const float4* Wg = (const float4*)(W + (size_t)d0 * DR);
#pragma unroll
  for (int i = 0; i < 4; ++i) {
    int idx4 = t + 256 * i;
    int r  = idx4 >> 4;           // row within tile
    int k4 = (idx4 & 15) * 4;     // starting k
    float4 va = Ag[idx4];
    At[k4 + 0][r] = va.x; At[k4 + 1][r] = va.y; At[k4 + 2][r] = va.z; At[k4 + 3][r] = va.w;
    float4 vw = Wg[idx4];
    Wt[k4 + 0][r] = vw.x; Wt[k4 + 1][r] = vw.y; Wt[k4 + 2][r] = vw.z; Wt[k4 + 3][r] = vw.w;
  }
  __syncthreads();
  int mg = t >> 4, ng = t & 15;   // m = mg*4+i, n = ng*4+j
  float acc[4][4] = {};
#pragma unroll
  for (int k = 0; k < 64; ++k) {
    float4 am = *(const float4*)&At[k][mg * 4];
    float4 wn = *(const float4*)&Wt[k][ng * 4];
#pragma unroll
    for (int i = 0; i < 4; ++i) {
      float a = (i == 0) ? am.x : (i == 1) ? am.y : (i == 2) ? am.z : am.w;
      acc[i][0] = fmaf(a, wn.x, acc[i][0]);
      acc[i][1] = fmaf(a, wn.y, acc[i][1]);
      acc[i][2] = fmaf(a, wn.z, acc[i][2]);
      acc[i][3] = fmaf(a, wn.w, acc[i][3]);
    }
  }
  float4 bb = *(const float4*)&bias[d0 + ng * 4];
#pragma unroll
  for (int i = 0; i < 4; ++i) {
    int m = m0 + mg * 4 + i;
    float4 o;
    o.x = softplusf(acc[i][0] + 2.f * bb.x);
    o.y = softplusf(acc[i][1] + 2.f * bb.y);
    o.z = softplusf(acc[i][2] + 2.f * bb.z);
    o.w = softplusf(acc[i][3] + 2.f * bb.w);
    *(float4*)&dt[(size_t)m * DM + d0 + ng * 4] = o;
  }
}

// ---------------- K2a: Bm/Cm partials, split-K ----------------
// Out[4096 x 32] = x[4096 x 1024] * Wcat[32 x 1024]^T, Mtile=64, Ksplit=8 (Kchunk=128)
__global__ __launch_bounds__(256) void k_bcm_part(const float* __restrict__ x,
                                                  const float* __restrict__ BW,
                                                  const float* __restrict__ CW,
                                                  float* __restrict__ part) {
  __shared__ __align__(16) float xt[64][132];
  __shared__ __align__(16) float wt[32][132];
  int mt = blockIdx.x >> 3, ks = blockIdx.x & 7;
  int m0 = mt * 64, k0 = ks * 128;
  int t = threadIdx.x;
#pragma unroll
  for (int i = 0; i < 8; ++i) {   // 64 rows x 32 float4
    int idx4 = t + 256 * i;
    int r = idx4 >> 5, c4 = idx4 & 31;
    float4 v = *(const float4*)&x[(size_t)(m0 + r) * DM + k0 + c4 * 4];
    *(float4*)&xt[r][c4 * 4] = v;
  }
#pragma unroll
  for (int i = 0; i < 4; ++i) {   // 32 rows x 32 float4
    int idx4 = t + 256 * i;
    int n = idx4 >> 5, c4 = idx4 & 31;
    const float* src = (n < 16) ? &BW[(size_t)n * DM + k0 + c4 * 4]
                                : &CW[(size_t)(n - 16) * DM + k0 + c4 * 4];
    *(float4*)&wt[n][c4 * 4] = *(const float4*)src;
  }
  __syncthreads();
  int lg = t >> 3, ng = t & 7;    // l = lg*2+i, n = ng*4+j
  float acc[2][4] = {};
#pragma unroll 4
  for (int k4 = 0; k4 < 32; ++k4) {
    float4 xa0 = *(const float4*)&xt[lg * 2 + 0][k4 * 4];
    float4 xa1 = *(const float4*)&xt[lg * 2 + 1][k4 * 4];
#pragma unroll
    for (int j = 0; j < 4; ++j) {
      float4 w = *(const float4*)&wt[ng * 4 + j][k4 * 4];
      fma4(acc[0][j], xa0, w);
      fma4(acc[1][j], xa1, w);
    }
  }
#pragma unroll
  for (int i = 0; i < 2; ++i) {
    float4 o = make_float4(acc[i][0], acc[i][1], acc[i][2], acc[i][3]);
    *(float4*)&part[(size_t)ks * (4096 * 32) + (size_t)(m0 + lg * 2 + i) * 32 + ng * 4] = o;
  }
}

// ---------------- K2b: reduce split-K partials into Bm / Cm ----------------
__global__ __launch_bounds__(256) void k_bcm_reduce(const float* __restrict__ part,
                                                    float* __restrict__ Bm,
                                                    float* __restrict__ Cm) {
#pragma unroll
  for (int i = 0; i < 4; ++i) {
    int id = blockIdx.x * 1024 + threadIdx.x + 256 * i;
    float s = 0.f;
#pragma unroll
    for (int ks = 0; ks < 8; ++ks) s += part[(size_t)ks * (4096 * 32) + id];
    int bl = id >> 5, n = id & 31;
    if (n < 16) Bm[(size_t)bl * DS + n] = s;
    else        Cm[(size_t)bl * DS + (n - 16)] = s;
  }
}

// ---------------- Phase 1: chunk-local scan from h=0; store Sum(dt), h_end ----------------
__global__ __launch_bounds__(256) void k_phase1(const float* __restrict__ x,
                                                const float* __restrict__ dt,
                                                const float* __restrict__ Bm,
                                                const float* __restrict__ A_log,
                                                float* __restrict__ Ssum,
                                                float* __restrict__ hend) {
  __shared__ float bml[CL * DS];  // 512 floats
  int bid = blockIdx.x;
  int b = bid >> 8, rem = bid & 255;
  int c = rem >> 2, dg = rem & 3;
  int t = threadIdx.x;
  int d = dg * 256 + t;
  const float* bsrc = Bm + ((size_t)b * SEQ + c * CL) * DS;
  *(float2*)&bml[t * 2] = *(const float2*)&bsrc[t * 2];
  __syncthreads();
  float a2[16];
#pragma unroll
  for (int n = 0; n < 16; ++n)
    a2[n] = -__builtin_amdgcn_exp2f(A_log[n] * LOG2E) * LOG2E;  // A[n]*log2(e)
  float h[16] = {};
  float S = 0.f;
  size_t base = ((size_t)b * SEQ + c * CL) * DM + d;
#pragma unroll 2
  for (int l = 0; l < CL; ++l) {
    float dtv = dt[base + (size_t)l * DM];
    float xv  = x[base + (size_t)l * DM];
    S += dtv;
    float dtx = dtv * xv;
#pragma unroll
    for (int n = 0; n < 16; ++n) {
      float a = __builtin_amdgcn_exp2f(dtv * a2[n]);
      h[n] = fmaf(a, h[n], dtx * bml[l * DS + n]);
    }
  }
  size_t cc = (size_t)b * NC + c;
  Ssum[cc * DM + d] = S;
#pragma unroll
  for (int n = 0; n < 16; ++n) hend[(cc * DS + n) * DM + d] = h[n];
}

// ---------------- Phase 2: sequential scan over chunk summaries ----------------
__global__ __launch_bounds__(256) void k_phase2(const float* __restrict__ A_log,
                                                const float* __restrict__ Ssum,
                                                const float* __restrict__ hend,
                                                float* __restrict__ hin) {
  int bid = blockIdx.x;            // 2 * 16 * 4 = 128
  int b = bid >> 6, rem = bid & 63;
  int n = rem >> 2, dg = rem & 3;
  int d = dg * 256 + threadIdx.x;
  float a2 = -__builtin_amdgcn_exp2f(A_log[n] * LOG2E) * LOG2E;
  float h = 0.f;
  for (int c = 0; c < NC; ++c) {
    size_t cc = (size_t)b * NC + c;
    hin[(cc * DS + n) * DM + d] = h;
    float aa = __builtin_amdgcn_exp2f(a2 * Ssum[cc * DM + d]);
    h = fmaf(aa, h, hend[(cc * DS + n) * DM + d]);
  }
}

// ---------------- Phase 3: re-run chunks from correct h_in, emit y ----------------
__global__ __launch_bounds__(256) void k_phase3(const float* __restrict__ x,
                                                const float* __restrict__ dt,
                                                const float* __restrict__ Bm,
                                                const float* __restrict__ Cm,
                                                const float* __restrict__ A_log,
                                                const float* __restrict__ Dvec,
                                                const float* __restrict__ hin,
                                                float* __restrict__ out) {
  __shared__ float bml[CL * DS], cml[CL * DS];
  int bid = blockIdx.x;
  int b = bid >> 8, rem = bid & 255;
  int c = rem >> 2, dg = rem & 3;
  int t = threadIdx.x;
  int d = dg * 256 + t;
  const float* bsrc = Bm + ((size_t)b * SEQ + c * CL) * DS;
  const float* csrc = Cm + ((size_t)b * SEQ + c * CL) * DS;
  *(float2*)&bml[t * 2] = *(const float2*)&bsrc[t * 2];
  *(float2*)&cml[t * 2] = *(const float2*)&csrc[t * 2];
  __syncthreads();
  float a2[16];
#pragma unroll
  for (int n = 0; n < 16; ++n)
    a2[n] = -__builtin_amdgcn_exp2f(A_log[n] * LOG2E) * LOG2E;
  size_t cc = (size_t)b * NC + c;
  float h[16];
#pragma unroll
  for (int n = 0; n < 16; ++n) h[n] = hin[(cc * DS + n) * DM + d];
  float dv = Dvec[d];
  size_t base = ((size_t)b * SEQ + c * CL) * DM + d;
#pragma unroll 2
  for (int l = 0; l < CL; ++l) {
    float dtv = dt[base + (size_t)l * DM];
    float xv  = x[base + (size_t)l * DM];
    float dtx = dtv * xv;
    float y = 0.f;
#pragma unroll
    for (int n = 0; n < 16; ++n) {
      float a = __builtin_amdgcn_exp2f(dtv * a2[n]);
      h[n] = fmaf(a, h[n], dtx * bml[l * DS + n]);
      y = fmaf(h[n], cml[l * DS + n], y);
    }
    out[base + (size_t)l * DM] = fmaf(xv, dv, y);
  }
}

extern "C" void kernel_launch(void* const* d_in, const int* in_sizes, int n_in,
                              void* d_out, int out_size, void* d_ws, size_t ws_size,
                              hipStream_t stream) {
  (void)in_sizes; (void)n_in; (void)out_size; (void)ws_size;
  const float* x     = (const float*)d_in[0];
  const float* dtp   = (const float*)d_in[1];
  const float* A_log = (const float*)d_in[2];
  const float* dtW   = (const float*)d_in[3];
  const float* dtb   = (const float*)d_in[4];
  const float* BW    = (const float*)d_in[5];
  const float* CW    = (const float*)d_in[6];
  const float* Dv    = (const float*)d_in[7];
  float* out = (float*)d_out;
  float* ws  = (float*)d_ws;

  float* dt   = ws + OFF_DT;
  float* Bm   = ws + OFF_BM;
  float* Cm   = ws + OFF_CM;
  float* S    = ws + OFF_S;
  float* hend = ws + OFF_HEND;
  float* hin  = ws + OFF_HIN;
  float* part = ws + OFF_PART;   // aliases hend region (dead at that time)

  k_dtproj    <<<1024, 256, 0, stream>>>(dtp, dtW, dtb, dt);
  k_bcm_part  <<<512,  256, 0, stream>>>(x, BW, CW, part);
  k_bcm_reduce<<<128,  256, 0, stream>>>(part, Bm, Cm);
  k_phase1    <<<512,  256, 0, stream>>>(x, dt, Bm, A_log, S, hend);
  k_phase2    <<<128,  256, 0, stream>>>(A_log, S, hend, hin);
  k_phase3    <<<512,  256, 0, stream>>>(x, dt, Bm, Cm, A_log, Dv, hin, out);
}

// Round 2
// 77.609 us; speedup vs baseline: 1.7676x; 1.7676x over previous
//
#include <hip/hip_runtime.h>

#define LOG2E 1.44269504088896340736f
#define LN2   0.69314718055994530942f

constexpr int BSZ = 2, SEQ = 2048, DM = 1024, DS = 16, DR = 64;
constexpr int NC = 64, CL = SEQ / NC;   // 64 chunks of 32

// Workspace layout (in floats)
constexpr size_t OFF_DT   = 0;                       // [4096][1024]
constexpr size_t OFF_BM   = OFF_DT + (size_t)BSZ*SEQ*DM;      // [4096][16]
constexpr size_t OFF_CM   = OFF_BM + (size_t)BSZ*SEQ*DS;      // [4096][16]
constexpr size_t OFF_S    = OFF_CM + (size_t)BSZ*SEQ*DS;      // [B][NC][1024]
constexpr size_t OFF_HEND = OFF_S  + (size_t)BSZ*NC*DM;       // [B][NC][16][1024]
constexpr size_t OFF_HIN  = OFF_HEND + (size_t)BSZ*NC*DS*DM;  // [B][NC][16][1024]
constexpr size_t OFF_PART = OFF_HEND;  // K2 partials alias hend (used before phase1)
// total = 8,650,752 floats = 34.6 MB

__device__ inline float softplusf(float z) {
  float e = __builtin_amdgcn_exp2f(z * LOG2E);
  if (z > 15.f) return z;
  if (z < -8.f) return e;                      // log1p(e) ~ e
  return __builtin_amdgcn_logf(1.f + e) * LN2; // v_log is log2
}

__device__ inline void fma4(float& acc, float4 a, float4 b) {
  acc = fmaf(a.x, b.x, fmaf(a.y, b.y, fmaf(a.z, b.z, fmaf(a.w, b.w, acc))));
}

// ---------------- K1: dt = softplus(dt_proj_input @ dt_W^T + 2*dt_b) ----------------
// C[4096 x 1024] = A[4096 x 64] * W[1024 x 64]^T
// Tile 64m x 128n, 256 threads, thread tile 4m x 8n, outer-product over k.
// LDS layouts [k][m] stride 66, [k][n] stride 130: transposed scalar stores hit
// bank (2k+m)%32 -> 4-way worst case; float2 reads 8B-aligned.
__global__ __launch_bounds__(256, 3) void k_dtproj(const float* __restrict__ inp,
                                                   const float* __restrict__ W,
                                                   const float* __restrict__ bias,
                                                   float* __restrict__ dt) {
  __shared__ __align__(16) float At[64][66];   // [k][m]
  __shared__ __align__(16) float Wt[64][130];  // [k][n]
  int mt = blockIdx.x >> 3, nt = blockIdx.x & 7;
  int m0 = mt * 64, n0 = nt * 128;
  int t = threadIdx.x;
  // load A tile: 64 rows x 16 float4 (along k)
#pragma unroll
  for (int i = 0; i < 4; ++i) {
    int idx4 = t + 256 * i;              // 0..1023
    int m = idx4 >> 4, k4 = (idx4 & 15) * 4;
    float4 v = *(const float4*)&inp[(size_t)(m0 + m) * DR + k4];
    At[k4 + 0][m] = v.x; At[k4 + 1][m] = v.y; At[k4 + 2][m] = v.z; At[k4 + 3][m] = v.w;
  }
  // load W tile: 128 rows x 16 float4 (along k)
#pragma unroll
  for (int i = 0; i < 8; ++i) {
    int idx4 = t + 256 * i;              // 0..2047
    int n = idx4 >> 4, k4 = (idx4 & 15) * 4;
    float4 v = *(const float4*)&W[(size_t)(n0 + n) * DR + k4];
    Wt[k4 + 0][n] = v.x; Wt[k4 + 1][n] = v.y; Wt[k4 + 2][n] = v.z; Wt[k4 + 3][n] = v.w;
  }
  __syncthreads();
  int mg = t >> 4, ng = t & 15;          // m = mg*4+i, n = ng*8+j
  float acc[4][8] = {};
#pragma unroll 4
  for (int k = 0; k < 64; ++k) {
    float2 a01 = *(const float2*)&At[k][mg * 4];
    float2 a23 = *(const float2*)&At[k][mg * 4 + 2];
    float a[4] = {a01.x, a01.y, a23.x, a23.y};
    float w[8];
#pragma unroll
    for (int u = 0; u < 4; ++u) {
      float2 wv = *(const float2*)&Wt[k][ng * 8 + 2 * u];
      w[2 * u] = wv.x; w[2 * u + 1] = wv.y;
    }
#pragma unroll
    for (int i = 0; i < 4; ++i)
#pragma unroll
      for (int j = 0; j < 8; ++j)
        acc[i][j] = fmaf(a[i], w[j], acc[i][j]);
  }
  float bb[8];
  *(float4*)&bb[0] = *(const float4*)&bias[n0 + ng * 8];
  *(float4*)&bb[4] = *(const float4*)&bias[n0 + ng * 8 + 4];
#pragma unroll
  for (int i = 0; i < 4; ++i) {
    int m = m0 + mg * 4 + i;
    float o[8];
#pragma unroll
    for (int j = 0; j < 8; ++j) o[j] = softplusf(acc[i][j] + 2.f * bb[j]);
    *(float4*)&dt[(size_t)m * DM + n0 + ng * 8]     = make_float4(o[0], o[1], o[2], o[3]);
    *(float4*)&dt[(size_t)m * DM + n0 + ng * 8 + 4] = make_float4(o[4], o[5], o[6], o[7]);
  }
}

// ---------------- K2a: Bm/Cm partials, split-K ----------------
// Out[4096 x 32] = x[4096 x 1024] * Wcat[32 x 1024]^T, Mtile=64, Ksplit=8 (Kchunk=128)
__global__ __launch_bounds__(256) void k_bcm_part(const float* __restrict__ x,
                                                  const float* __restrict__ BW,
                                                  const float* __restrict__ CW,
                                                  float* __restrict__ part) {
  __shared__ __align__(16) float xt[64][132];
  __shared__ __align__(16) float wt[32][132];
  int mt = blockIdx.x >> 3, ks = blockIdx.x & 7;
  int m0 = mt * 64, k0 = ks * 128;
  int t = threadIdx.x;
#pragma unroll
  for (int i = 0; i < 8; ++i) {   // 64 rows x 32 float4
    int idx4 = t + 256 * i;
    int r = idx4 >> 5, c4 = idx4 & 31;
    float4 v = *(const float4*)&x[(size_t)(m0 + r) * DM + k0 + c4 * 4];
    *(float4*)&xt[r][c4 * 4] = v;
  }
#pragma unroll
  for (int i = 0; i < 4; ++i) {   // 32 rows x 32 float4
    int idx4 = t + 256 * i;
    int n = idx4 >> 5, c4 = idx4 & 31;
    const float* src = (n < 16) ? &BW[(size_t)n * DM + k0 + c4 * 4]
                                : &CW[(size_t)(n - 16) * DM + k0 + c4 * 4];
    *(float4*)&wt[n][c4 * 4] = *(const float4*)src;
  }
  __syncthreads();
  int lg = t >> 3, ng = t & 7;    // l = lg*2+i, n = ng*4+j
  float acc[2][4] = {};
#pragma unroll 4
  for (int k4 = 0; k4 < 32; ++k4) {
    float4 xa0 = *(const float4*)&xt[lg * 2 + 0][k4 * 4];
    float4 xa1 = *(const float4*)&xt[lg * 2 + 1][k4 * 4];
#pragma unroll
    for (int j = 0; j < 4; ++j) {
      float4 w = *(const float4*)&wt[ng * 4 + j][k4 * 4];
      fma4(acc[0][j], xa0, w);
      fma4(acc[1][j], xa1, w);
    }
  }
#pragma unroll
  for (int i = 0; i < 2; ++i) {
    float4 o = make_float4(acc[i][0], acc[i][1], acc[i][2], acc[i][3]);
    *(float4*)&part[(size_t)ks * (4096 * 32) + (size_t)(m0 + lg * 2 + i) * 32 + ng * 4] = o;
  }
}

// ---------------- K2b: reduce split-K partials into Bm / Cm ----------------
__global__ __launch_bounds__(256) void k_bcm_reduce(const float* __restrict__ part,
                                                    float* __restrict__ Bm,
                                                    float* __restrict__ Cm) {
#pragma unroll
  for (int i = 0; i < 4; ++i) {
    int id = blockIdx.x * 1024 + threadIdx.x + 256 * i;
    float s = 0.f;
#pragma unroll
    for (int ks = 0; ks < 8; ++ks) s += part[(size_t)ks * (4096 * 32) + id];
    int bl = id >> 5, n = id & 31;
    if (n < 16) Bm[(size_t)bl * DS + n] = s;
    else        Cm[(size_t)bl * DS + (n - 16)] = s;
  }
}

// ---------------- Phase 1: chunk-local scan from h=0; store Sum(dt), h_end ----------------
__global__ __launch_bounds__(256) void k_phase1(const float* __restrict__ x,
                                                const float* __restrict__ dt,
                                                const float* __restrict__ Bm,
                                                const float* __restrict__ A_log,
                                                float* __restrict__ Ssum,
                                                float* __restrict__ hend) {
  __shared__ float bml[CL * DS];  // 512 floats
  int bid = blockIdx.x;
  int b = bid >> 8, rem = bid & 255;
  int c = rem >> 2, dg = rem & 3;
  int t = threadIdx.x;
  int d = dg * 256 + t;
  const float* bsrc = Bm + ((size_t)b * SEQ + c * CL) * DS;
  *(float2*)&bml[t * 2] = *(const float2*)&bsrc[t * 2];
  __syncthreads();
  float a2[16];
#pragma unroll
  for (int n = 0; n < 16; ++n)
    a2[n] = -__builtin_amdgcn_exp2f(A_log[n] * LOG2E) * LOG2E;  // A[n]*log2(e)
  float h[16] = {};
  float S = 0.f;
  size_t base = ((size_t)b * SEQ + c * CL) * DM + d;
#pragma unroll 2
  for (int l = 0; l < CL; ++l) {
    float dtv = dt[base + (size_t)l * DM];
    float xv  = x[base + (size_t)l * DM];
    S += dtv;
    float dtx = dtv * xv;
#pragma unroll
    for (int n = 0; n < 16; ++n) {
      float a = __builtin_amdgcn_exp2f(dtv * a2[n]);
      h[n] = fmaf(a, h[n], dtx * bml[l * DS + n]);
    }
  }
  size_t cc = (size_t)b * NC + c;
  Ssum[cc * DM + d] = S;
#pragma unroll
  for (int n = 0; n < 16; ++n) hend[(cc * DS + n) * DM + d] = h[n];
}

// ---------------- Phase 2: sequential scan over chunk summaries ----------------
__global__ __launch_bounds__(256) void k_phase2(const float* __restrict__ A_log,
                                                const float* __restrict__ Ssum,
                                                const float* __restrict__ hend,
                                                float* __restrict__ hin) {
  int bid = blockIdx.x;            // 2 * 16 * 4 = 128
  int b = bid >> 6, rem = bid & 63;
  int n = rem >> 2, dg = rem & 3;
  int d = dg * 256 + threadIdx.x;
  float a2 = -__builtin_amdgcn_exp2f(A_log[n] * LOG2E) * LOG2E;
  float h = 0.f;
  for (int c = 0; c < NC; ++c) {
    size_t cc = (size_t)b * NC + c;
    hin[(cc * DS + n) * DM + d] = h;
    float aa = __builtin_amdgcn_exp2f(a2 * Ssum[cc * DM + d]);
    h = fmaf(aa, h, hend[(cc * DS + n) * DM + d]);
  }
}

// ---------------- Phase 3: re-run chunks from correct h_in, emit y ----------------
__global__ __launch_bounds__(256) void k_phase3(const float* __restrict__ x,
                                                const float* __restrict__ dt,
                                                const float* __restrict__ Bm,
                                                const float* __restrict__ Cm,
                                                const float* __restrict__ A_log,
                                                const float* __restrict__ Dvec,
                                                const float* __restrict__ hin,
                                                float* __restrict__ out) {
  __shared__ float bml[CL * DS], cml[CL * DS];
  int bid = blockIdx.x;
  int b = bid >> 8, rem = bid & 255;
  int c = rem >> 2, dg = rem & 3;
  int t = threadIdx.x;
  int d = dg * 256 + t;
  const float* bsrc = Bm + ((size_t)b * SEQ + c * CL) * DS;
  const float* csrc = Cm + ((size_t)b * SEQ + c * CL) * DS;
  *(float2*)&bml[t * 2] = *(const float2*)&bsrc[t * 2];
  *(float2*)&cml[t * 2] = *(const float2*)&csrc[t * 2];
  __syncthreads();
  float a2[16];
#pragma unroll
  for (int n = 0; n < 16; ++n)
    a2[n] = -__builtin_amdgcn_exp2f(A_log[n] * LOG2E) * LOG2E;
  size_t cc = (size_t)b * NC + c;
  float h[16];
#pragma unroll
  for (int n = 0; n < 16; ++n) h[n] = hin[(cc * DS + n) * DM + d];
  float dv = Dvec[d];
  size_t base = ((size_t)b * SEQ + c * CL) * DM + d;
#pragma unroll 2
  for (int l = 0; l < CL; ++l) {
    float dtv = dt[base + (size_t)l * DM];
    float xv  = x[base + (size_t)l * DM];
    float dtx = dtv * xv;
    float y = 0.f;
#pragma unroll
    for (int n = 0; n < 16; ++n) {
      float a = __builtin_amdgcn_exp2f(dtv * a2[n]);
      h[n] = fmaf(a, h[n], dtx * bml[l * DS + n]);
      y = fmaf(h[n], cml[l * DS + n], y);
    }
    out[base + (size_t)l * DM] = fmaf(xv, dv, y);
  }
}

extern "C" void kernel_launch(void* const* d_in, const int* in_sizes, int n_in,
                              void* d_out, int out_size, void* d_ws, size_t ws_size,
                              hipStream_t stream) {
  (void)in_sizes; (void)n_in; (void)out_size; (void)ws_size;
  const float* x     = (const float*)d_in[0];
  const float* dtp   = (const float*)d_in[1];
  const float* A_log = (const float*)d_in[2];
  const float* dtW   = (const float*)d_in[3];
  const float* dtb   = (const float*)d_in[4];
  const float* BW    = (const float*)d_in[5];
  const float* CW    = (const float*)d_in[6];
  const float* Dv    = (const float*)d_in[7];
  float* out = (float*)d_out;
  float* ws  = (float*)d_ws;

  float* dt   = ws + OFF_DT;
  float* Bm   = ws + OFF_BM;
  float* Cm   = ws + OFF_CM;
  float* S    = ws + OFF_S;
  float* hend = ws + OFF_HEND;
  float* hin  = ws + OFF_HIN;
  float* part = ws + OFF_PART;   // aliases hend region (dead at that time)

  k_dtproj    <<<512,  256, 0, stream>>>(dtp, dtW, dtb, dt);
  k_bcm_part  <<<512,  256, 0, stream>>>(x, BW, CW, part);
  k_bcm_reduce<<<128,  256, 0, stream>>>(part, Bm, Cm);
  k_phase1    <<<512,  256, 0, stream>>>(x, dt, Bm, A_log, S, hend);
  k_phase2    <<<128,  256, 0, stream>>>(A_log, S, hend, hin);
  k_phase3    <<<512,  256, 0, stream>>>(x, dt, Bm, Cm, A_log, Dv, hin, out);
}

// Round 3
// 64.397 us; speedup vs baseline: 2.1303x; 1.2052x over previous
//
#include <hip/hip_runtime.h>

#define LOG2E 1.44269504088896340736f
#define LN2   0.69314718055994530942f

constexpr int BSZ = 2, SEQ = 2048, DM = 1024, DS = 16, DR = 64;
constexpr int NC = 64, CL = SEQ / NC;   // 64 chunks of 32

// Workspace layout (in floats)
constexpr size_t OFF_DT   = 0;                                // [4096][1024]
constexpr size_t OFF_BM   = OFF_DT + (size_t)BSZ*SEQ*DM;      // [4096][16]
constexpr size_t OFF_CM   = OFF_BM + (size_t)BSZ*SEQ*DS;      // [4096][16]
constexpr size_t OFF_S    = OFF_CM + (size_t)BSZ*SEQ*DS;      // [B][NC][1024]
constexpr size_t OFF_HEND = OFF_S  + (size_t)BSZ*NC*DM;       // [B][NC][16][1024]
constexpr size_t OFF_HIN  = OFF_HEND + (size_t)BSZ*NC*DS*DM;  // [B][NC][16][1024]
constexpr size_t OFF_PART = OFF_HIN  + (size_t)BSZ*NC*DS*DM;  // [8][4096][32]
// total = 9,699,328 floats = 38.8 MB  (ws = 256 MiB per harness fill)

__device__ inline float softplusf(float z) {
  float e = __builtin_amdgcn_exp2f(z * LOG2E);
  if (z > 15.f) return z;
  if (z < -8.f) return e;                      // log1p(e) ~ e
  return __builtin_amdgcn_logf(1.f + e) * LN2; // v_log is log2
}

__device__ inline void fma4(float& acc, float4 a, float4 b) {
  acc = fmaf(a.x, b.x, fmaf(a.y, b.y, fmaf(a.z, b.z, fmaf(a.w, b.w, acc))));
}

// ================= K_front: dtproj (blocks 0..255) | bcm_part (blocks 256..767) ==========
// dtproj: C[4096x1024] = A[4096x64] * W[1024x64]^T, tile 128m x 128n, thread 8x8.
//   LDS [k][m]/[k][n] stride 132: A-frag b128 reads broadcast (banks 8mg..8mg+3, CF);
//   W-frag b128 at ng*4 / ng*4+64 -> 2-way (free).
// bcm: Out[4096x32] = x * [BW;CW]^T, Mtile 64, Ksplit 8 (Kchunk 128), thread 2m x 4n,
//   n interleaved (n = ng + 8j) -> w-read banks 4ng (8 quads, CF).
__global__ __launch_bounds__(256, 2) void k_front(const float* __restrict__ inp,
                                                  const float* __restrict__ W,
                                                  const float* __restrict__ bias,
                                                  float* __restrict__ dt,
                                                  const float* __restrict__ x,
                                                  const float* __restrict__ BW,
                                                  const float* __restrict__ CW,
                                                  float* __restrict__ part) {
  __shared__ __align__(16) float smem[16896];   // 67.6 KB
  int bid = blockIdx.x;
  int t = threadIdx.x;
  if (bid < 256) {
    // ---------------- dtproj ----------------
    float* At = smem;              // [64][132], [k][m]
    float* Wt = smem + 64 * 132;   // [64][132], [k][n]
    int mt = bid >> 3, nt = bid & 7;
    int m0 = mt * 128, n0 = nt * 128;
#pragma unroll
    for (int i = 0; i < 8; ++i) {
      int idx4 = t + 256 * i;                   // 0..2047
      int m = idx4 >> 4, k4 = (idx4 & 15) * 4;
      float4 v = *(const float4*)&inp[(size_t)(m0 + m) * DR + k4];
      At[(k4 + 0) * 132 + m] = v.x; At[(k4 + 1) * 132 + m] = v.y;
      At[(k4 + 2) * 132 + m] = v.z; At[(k4 + 3) * 132 + m] = v.w;
    }
#pragma unroll
    for (int i = 0; i < 8; ++i) {
      int idx4 = t + 256 * i;
      int n = idx4 >> 4, k4 = (idx4 & 15) * 4;
      float4 v = *(const float4*)&W[(size_t)(n0 + n) * DR + k4];
      Wt[(k4 + 0) * 132 + n] = v.x; Wt[(k4 + 1) * 132 + n] = v.y;
      Wt[(k4 + 2) * 132 + n] = v.z; Wt[(k4 + 3) * 132 + n] = v.w;
    }
    __syncthreads();
    int mg = t >> 4, ng = t & 15;   // m = mg*8+i ; n = ng*4+j (j<4), 64+ng*4+(j-4)
    float acc[8][8] = {};
#pragma unroll 4
    for (int k = 0; k < 64; ++k) {
      const float* rowA = At + k * 132;
      const float* rowW = Wt + k * 132;
      float4 a0 = *(const float4*)&rowA[mg * 8];
      float4 a1 = *(const float4*)&rowA[mg * 8 + 4];
      float4 w0 = *(const float4*)&rowW[ng * 4];
      float4 w1 = *(const float4*)&rowW[ng * 4 + 64];
      float a[8] = {a0.x, a0.y, a0.z, a0.w, a1.x, a1.y, a1.z, a1.w};
      float w[8] = {w0.x, w0.y, w0.z, w0.w, w1.x, w1.y, w1.z, w1.w};
#pragma unroll
      for (int i = 0; i < 8; ++i)
#pragma unroll
        for (int j = 0; j < 8; ++j)
          acc[i][j] = fmaf(a[i], w[j], acc[i][j]);
    }
    float4 b0 = *(const float4*)&bias[n0 + ng * 4];
    float4 b1 = *(const float4*)&bias[n0 + ng * 4 + 64];
    float bb[8] = {b0.x, b0.y, b0.z, b0.w, b1.x, b1.y, b1.z, b1.w};
#pragma unroll
    for (int i = 0; i < 8; ++i) {
      int m = m0 + mg * 8 + i;
      float4 lo, hi;
      lo.x = softplusf(acc[i][0] + 2.f * bb[0]);
      lo.y = softplusf(acc[i][1] + 2.f * bb[1]);
      lo.z = softplusf(acc[i][2] + 2.f * bb[2]);
      lo.w = softplusf(acc[i][3] + 2.f * bb[3]);
      hi.x = softplusf(acc[i][4] + 2.f * bb[4]);
      hi.y = softplusf(acc[i][5] + 2.f * bb[5]);
      hi.z = softplusf(acc[i][6] + 2.f * bb[6]);
      hi.w = softplusf(acc[i][7] + 2.f * bb[7]);
      *(float4*)&dt[(size_t)m * DM + n0 + ng * 4]      = lo;
      *(float4*)&dt[(size_t)m * DM + n0 + ng * 4 + 64] = hi;
    }
  } else {
    // ---------------- bcm_part ----------------
    float* xt = smem;              // [64][132]
    float* wt = smem + 64 * 132;   // [32][132]
    int bid2 = bid - 256;
    int mt = bid2 >> 3, ks = bid2 & 7;
    int m0 = mt * 64, k0 = ks * 128;
#pragma unroll
    for (int i = 0; i < 8; ++i) {   // 64 rows x 32 float4
      int idx4 = t + 256 * i;
      int r = idx4 >> 5, c4 = (idx4 & 31) * 4;
      float4 v = *(const float4*)&x[(size_t)(m0 + r) * DM + k0 + c4];
      *(float4*)&xt[r * 132 + c4] = v;
    }
#pragma unroll
    for (int i = 0; i < 4; ++i) {   // 32 rows x 32 float4
      int idx4 = t + 256 * i;
      int n = idx4 >> 5, c4 = (idx4 & 31) * 4;
      const float* src = (n < 16) ? &BW[(size_t)n * DM + k0 + c4]
                                  : &CW[(size_t)(n - 16) * DM + k0 + c4];
      *(float4*)&wt[n * 132 + c4] = *(const float4*)src;
    }
    __syncthreads();
    int lg = t >> 3, ng = t & 7;    // m = m0+lg*2+i ; n = ng + 8j
    float acc[2][4] = {};
#pragma unroll 4
    for (int k4 = 0; k4 < 32; ++k4) {
      float4 xa0 = *(const float4*)&xt[(lg * 2 + 0) * 132 + k4 * 4];
      float4 xa1 = *(const float4*)&xt[(lg * 2 + 1) * 132 + k4 * 4];
#pragma unroll
      for (int j = 0; j < 4; ++j) {
        float4 w = *(const float4*)&wt[(ng + 8 * j) * 132 + k4 * 4];
        fma4(acc[0][j], xa0, w);
        fma4(acc[1][j], xa1, w);
      }
    }
#pragma unroll
    for (int i = 0; i < 2; ++i)
#pragma unroll
      for (int j = 0; j < 4; ++j)
        part[(size_t)ks * (4096 * 32) + (size_t)(m0 + lg * 2 + i) * 32 + ng + 8 * j] = acc[i][j];
  }
}

// ---------------- Phase 1: reduce part -> Bm (LDS); chunk-local scan; store Sum(dt), h_end ---
// dg==0 blocks also emit reduced Bm and Cm to global for phase 3.
__global__ __launch_bounds__(256) void k_phase1(const float* __restrict__ x,
                                                const float* __restrict__ dt,
                                                const float* __restrict__ part,
                                                const float* __restrict__ A_log,
                                                float* __restrict__ Bm,
                                                float* __restrict__ Cm,
                                                float* __restrict__ Ssum,
                                                float* __restrict__ hend) {
  __shared__ float bml[CL * DS];  // 512 floats
  int bid = blockIdx.x;
  int b = bid >> 8, rem = bid & 255;
  int c = rem >> 2, dg = rem & 3;
  int t = threadIdx.x;
  int d = dg * 256 + t;
  size_t blbase = (size_t)b * SEQ + c * CL;
  {
    // thread t covers (l = t>>3, n = 2*(t&7)) as float2, summed over 8 k-splits
    size_t e = (blbase + (t >> 3)) * 32 + 2 * (t & 7);
    float2 s = make_float2(0.f, 0.f);
#pragma unroll
    for (int ks = 0; ks < 8; ++ks) {
      float2 v = *(const float2*)&part[(size_t)ks * (4096 * 32) + e];
      s.x += v.x; s.y += v.y;
    }
    *(float2*)&bml[t * 2] = s;
    if (dg == 0) {
      *(float2*)&Bm[(blbase + (t >> 3)) * DS + 2 * (t & 7)] = s;
      float2 sc = make_float2(0.f, 0.f);
#pragma unroll
      for (int ks = 0; ks < 8; ++ks) {
        float2 v = *(const float2*)&part[(size_t)ks * (4096 * 32) + e + 16];
        sc.x += v.x; sc.y += v.y;
      }
      *(float2*)&Cm[(blbase + (t >> 3)) * DS + 2 * (t & 7)] = sc;
    }
  }
  __syncthreads();
  float a2[16];
#pragma unroll
  for (int n = 0; n < 16; ++n)
    a2[n] = -__builtin_amdgcn_exp2f(A_log[n] * LOG2E) * LOG2E;  // A[n]*log2(e)
  float h[16] = {};
  float S = 0.f;
  size_t base = blbase * DM + d;
#pragma unroll 4
  for (int l = 0; l < CL; ++l) {
    float dtv = dt[base + (size_t)l * DM];
    float xv  = x[base + (size_t)l * DM];
    S += dtv;
    float dtx = dtv * xv;
#pragma unroll
    for (int n = 0; n < 16; ++n) {
      float a = __builtin_amdgcn_exp2f(dtv * a2[n]);
      h[n] = fmaf(a, h[n], dtx * bml[l * DS + n]);
    }
  }
  size_t cc = (size_t)b * NC + c;
  Ssum[cc * DM + d] = S;
#pragma unroll
  for (int n = 0; n < 16; ++n) hend[(cc * DS + n) * DM + d] = h[n];
}

// ---------------- Phase 2: sequential scan over chunk summaries ----------------
__global__ __launch_bounds__(256) void k_phase2(const float* __restrict__ A_log,
                                                const float* __restrict__ Ssum,
                                                const float* __restrict__ hend,
                                                float* __restrict__ hin) {
  int bid = blockIdx.x;            // 2 * 16 * 4 = 128
  int b = bid >> 6, rem = bid & 63;
  int n = rem >> 2, dg = rem & 3;
  int d = dg * 256 + threadIdx.x;
  float a2 = -__builtin_amdgcn_exp2f(A_log[n] * LOG2E) * LOG2E;
  float h = 0.f;
#pragma unroll 8
  for (int c = 0; c < NC; ++c) {
    size_t cc = (size_t)b * NC + c;
    hin[(cc * DS + n) * DM + d] = h;
    float aa = __builtin_amdgcn_exp2f(a2 * Ssum[cc * DM + d]);
    h = fmaf(aa, h, hend[(cc * DS + n) * DM + d]);
  }
}

// ---------------- Phase 3: re-run chunks from correct h_in, emit y ----------------
__global__ __launch_bounds__(256) void k_phase3(const float* __restrict__ x,
                                                const float* __restrict__ dt,
                                                const float* __restrict__ Bm,
                                                const float* __restrict__ Cm,
                                                const float* __restrict__ A_log,
                                                const float* __restrict__ Dvec,
                                                const float* __restrict__ hin,
                                                float* __restrict__ out) {
  __shared__ float bml[CL * DS], cml[CL * DS];
  int bid = blockIdx.x;
  int b = bid >> 8, rem = bid & 255;
  int c = rem >> 2, dg = rem & 3;
  int t = threadIdx.x;
  int d = dg * 256 + t;
  const float* bsrc = Bm + ((size_t)b * SEQ + c * CL) * DS;
  const float* csrc = Cm + ((size_t)b * SEQ + c * CL) * DS;
  *(float2*)&bml[t * 2] = *(const float2*)&bsrc[t * 2];
  *(float2*)&cml[t * 2] = *(const float2*)&csrc[t * 2];
  __syncthreads();
  float a2[16];
#pragma unroll
  for (int n = 0; n < 16; ++n)
    a2[n] = -__builtin_amdgcn_exp2f(A_log[n] * LOG2E) * LOG2E;
  size_t cc = (size_t)b * NC + c;
  float h[16];
#pragma unroll
  for (int n = 0; n < 16; ++n) h[n] = hin[(cc * DS + n) * DM + d];
  float dv = Dvec[d];
  size_t base = ((size_t)b * SEQ + c * CL) * DM + d;
#pragma unroll 4
  for (int l = 0; l < CL; ++l) {
    float dtv = dt[base + (size_t)l * DM];
    float xv  = x[base + (size_t)l * DM];
    float dtx = dtv * xv;
    float y = 0.f;
#pragma unroll
    for (int n = 0; n < 16; ++n) {
      float a = __builtin_amdgcn_exp2f(dtv * a2[n]);
      h[n] = fmaf(a, h[n], dtx * bml[l * DS + n]);
      y = fmaf(h[n], cml[l * DS + n], y);
    }
    out[base + (size_t)l * DM] = fmaf(xv, dv, y);
  }
}

extern "C" void kernel_launch(void* const* d_in, const int* in_sizes, int n_in,
                              void* d_out, int out_size, void* d_ws, size_t ws_size,
                              hipStream_t stream) {
  (void)in_sizes; (void)n_in; (void)out_size; (void)ws_size;
  const float* x     = (const float*)d_in[0];
  const float* dtp   = (const float*)d_in[1];
  const float* A_log = (const float*)d_in[2];
  const float* dtW   = (const float*)d_in[3];
  const float* dtb   = (const float*)d_in[4];
  const float* BW    = (const float*)d_in[5];
  const float* CW    = (const float*)d_in[6];
  const float* Dv    = (const float*)d_in[7];
  float* out = (float*)d_out;
  float* ws  = (float*)d_ws;

  float* dt   = ws + OFF_DT;
  float* Bm   = ws + OFF_BM;
  float* Cm   = ws + OFF_CM;
  float* S    = ws + OFF_S;
  float* hend = ws + OFF_HEND;
  float* hin  = ws + OFF_HIN;
  float* part = ws + OFF_PART;

  k_front <<<768, 256, 0, stream>>>(dtp, dtW, dtb, dt, x, BW, CW, part);
  k_phase1<<<512, 256, 0, stream>>>(x, dt, part, A_log, Bm, Cm, S, hend);
  k_phase2<<<128, 256, 0, stream>>>(A_log, S, hend, hin);
  k_phase3<<<512, 256, 0, stream>>>(x, dt, Bm, Cm, A_log, Dv, hin, out);
}